// Round 1
// baseline (78.390 us; speedup 1.0000x reference)
//
#include <hip/hip_runtime.h>
#include <hip/hip_bf16.h>
#include <stdint.h>

#define BATCH 16
#define NDIM  2048
#define MDIM  2048
#define DDIM  128   // LD == RD == 128

using bf16x8 = __attribute__((ext_vector_type(8))) short;
using f32x4  = __attribute__((ext_vector_type(4))) float;

// async global->LDS, 16B per lane; LDS dest is wave-uniform base + lane*16
#define GLOAD_LDS16(g, l) __builtin_amdgcn_global_load_lds( \
    (const __attribute__((address_space(1))) void*)(g),      \
    (__attribute__((address_space(3))) void*)(l), 16, 0, 0)

__device__ __forceinline__ unsigned short f2bf(float f) {
    unsigned u = __float_as_uint(f);
    u += 0x7fffu + ((u >> 16) & 1u);   // round-to-nearest-even
    return (unsigned short)(u >> 16);
}

// ---------------------------------------------------------------------------
// Kernel A: convert data, crit, W (f32) -> bf16 into workspace
// ---------------------------------------------------------------------------
extern "C" __global__ __launch_bounds__(256)
void bd_convert_kernel(const float* __restrict__ data,
                       const float* __restrict__ crit,
                       const float* __restrict__ W,
                       unsigned short* __restrict__ data_b,
                       unsigned short* __restrict__ crit_b,
                       unsigned short* __restrict__ w_b) {
    const size_t n1 = (size_t)BATCH * NDIM * DDIM / 4;  // float4 count
    const size_t n2 = (size_t)BATCH * MDIM * DDIM / 4;
    const size_t n3 = (size_t)DDIM * DDIM / 4;
    const size_t tot = n1 + n2 + n3;
    for (size_t i = (size_t)blockIdx.x * blockDim.x + threadIdx.x; i < tot;
         i += (size_t)gridDim.x * blockDim.x) {
        const float4* s; ushort4* d; size_t o;
        if (i < n1)            { s = (const float4*)data; d = (ushort4*)data_b; o = i; }
        else if (i < n1 + n2)  { s = (const float4*)crit; d = (ushort4*)crit_b; o = i - n1; }
        else                   { s = (const float4*)W;    d = (ushort4*)w_b;    o = i - n1 - n2; }
        float4 v = s[o];
        ushort4 r;
        r.x = f2bf(v.x); r.y = f2bf(v.y); r.z = f2bf(v.z); r.w = f2bf(v.w);
        d[o] = r;
    }
}

// ---------------------------------------------------------------------------
// Shared 128x128x128 bf16 MFMA tile: C_tile = A_tile(128xK128) * B_tile^T
// A rows and B^T rows both have 128 bf16 = 256 B, row-major, contiguous.
// LDS layout: [row][kseg^(row&15)] per 16B chunk (XOR swizzle, gload-compatible
// via pre-swizzled global source; read side applies the same XOR).
// ---------------------------------------------------------------------------
__device__ __forceinline__ void tile_gemm_128(const char* Ag, const char* Bg,
                                              char* smem, f32x4 (&acc)[4][4]) {
    const int t    = threadIdx.x;     // 0..255
    const int lane = t & 63;
    const int w    = t >> 6;          // wave 0..3

    #pragma unroll
    for (int m = 0; m < 4; ++m)
        #pragma unroll
        for (int n = 0; n < 4; ++n)
            acc[m][n] = (f32x4){0.f, 0.f, 0.f, 0.f};

    // Stage: A tile = chunks 0..2047 (LDS 0..32767), B tile = LDS 32768..65535.
    // chunk c -> (row = c>>4, kseg = c&15); source kseg pre-swizzled.
    #pragma unroll
    for (int it = 0; it < 8; ++it) {
        const int cb = it * 256 + w * 64;           // wave-uniform chunk base
        const int c  = cb + lane;
        const int row = c >> 4, ks = c & 15;
        const int ksrc = ks ^ (row & 15);
        GLOAD_LDS16(Ag + (size_t)row * 256 + ksrc * 16, smem + cb * 16);
        GLOAD_LDS16(Bg + (size_t)row * 256 + ksrc * 16, smem + 32768 + cb * 16);
    }
    __syncthreads();

    const int wr = w >> 1, wc = w & 1;       // 2x2 waves, 64x64 each
    const int lrow = lane & 15;
    const int lk   = lane >> 4;              // k-group 0..3

    #pragma unroll
    for (int ks = 0; ks < 4; ++ks) {         // 4 x K=32 substeps
        const int ksl = ks * 4 + lk;         // logical 16B kseg for this lane
        bf16x8 a[4], b[4];
        #pragma unroll
        for (int m = 0; m < 4; ++m) {
            const int r  = wr * 64 + m * 16 + lrow;
            const int kp = ksl ^ (r & 15);
            a[m] = *(const bf16x8*)(smem + r * 256 + kp * 16);
        }
        #pragma unroll
        for (int n = 0; n < 4; ++n) {
            const int r  = wc * 64 + n * 16 + lrow;
            const int kp = ksl ^ (r & 15);
            b[n] = *(const bf16x8*)(smem + 32768 + r * 256 + kp * 16);
        }
        #pragma unroll
        for (int m = 0; m < 4; ++m)
            #pragma unroll
            for (int n = 0; n < 4; ++n)
                acc[m][n] = __builtin_amdgcn_mfma_f32_16x16x32_bf16(
                    a[m], b[n], acc[m][n], 0, 0, 0);
    }
}

// ---------------------------------------------------------------------------
// Kernel B: cw[bm, i] = sum_j crit_b[bm, j] * W[i, j]   (B^T = W directly)
// M = 32768 flattened rows, N = 128, K = 128. Output bf16.
// ---------------------------------------------------------------------------
extern "C" __global__ __launch_bounds__(256)
void bd_gemm_cw_kernel(const unsigned short* __restrict__ crit_b,
                       const unsigned short* __restrict__ w_b,
                       unsigned short* __restrict__ cw) {
    __shared__ __align__(16) char smem[65536];
    const int br = blockIdx.x;  // 0..255
    const char* Ag = (const char*)crit_b + (size_t)br * 128 * 256;
    const char* Bg = (const char*)w_b;

    f32x4 acc[4][4];
    tile_gemm_128(Ag, Bg, smem, acc);

    const int t = threadIdx.x, lane = t & 63, w = t >> 6;
    const int wr = w >> 1, wc = w & 1, lrow = lane & 15, lk = lane >> 4;
    unsigned short* Cb = cw + (size_t)br * 128 * 128;
    #pragma unroll
    for (int m = 0; m < 4; ++m)
        #pragma unroll
        for (int n = 0; n < 4; ++n)
            #pragma unroll
            for (int j = 0; j < 4; ++j)
                Cb[(wr * 64 + m * 16 + lk * 4 + j) * 128 +
                   (wc * 64 + n * 16 + lrow)] = f2bf(acc[m][n][j]);
}

// ---------------------------------------------------------------------------
// Kernel C: dists[b, n, m] = sum_i data_b[b, n, i] * cw[b, m, i]
// Per batch: M=2048 x N=2048 x K=128. Output f32.
// ---------------------------------------------------------------------------
extern "C" __global__ __launch_bounds__(256)
void bd_gemm_main_kernel(const unsigned short* __restrict__ data_b,
                         const unsigned short* __restrict__ cw,
                         float* __restrict__ out) {
    __shared__ __align__(16) char smem[65536];
    const int bx = blockIdx.x;  // m tile 0..15
    const int by = blockIdx.y;  // n tile 0..15
    const int bz = blockIdx.z;  // batch 0..15
    const char* Ag = (const char*)data_b + ((size_t)bz * NDIM + by * 128) * DDIM * 2;
    const char* Bg = (const char*)cw     + ((size_t)bz * MDIM + bx * 128) * DDIM * 2;

    f32x4 acc[4][4];
    tile_gemm_128(Ag, Bg, smem, acc);

    const int t = threadIdx.x, lane = t & 63, w = t >> 6;
    const int wr = w >> 1, wc = w & 1, lrow = lane & 15, lk = lane >> 4;
    float* Cb = out + ((size_t)bz * NDIM + by * 128) * MDIM + bx * 128;
    #pragma unroll
    for (int m = 0; m < 4; ++m)
        #pragma unroll
        for (int n = 0; n < 4; ++n)
            #pragma unroll
            for (int j = 0; j < 4; ++j)
                Cb[(size_t)(wr * 64 + m * 16 + lk * 4 + j) * MDIM +
                   (wc * 64 + n * 16 + lrow)] = acc[m][n][j];
}

// ---------------------------------------------------------------------------
extern "C" void kernel_launch(void* const* d_in, const int* in_sizes, int n_in,
                              void* d_out, int out_size, void* d_ws, size_t ws_size,
                              hipStream_t stream) {
    const float* data = (const float*)d_in[0];  // [16,2048,128]
    const float* crit = (const float*)d_in[1];  // [16,2048,128]
    const float* W    = (const float*)d_in[2];  // [1,128,128]
    float* out = (float*)d_out;                 // [16,2048,2048]

    char* ws = (char*)d_ws;
    unsigned short* data_b = (unsigned short*)(ws);                       // 8 MB
    unsigned short* crit_b = (unsigned short*)(ws + 8388608);             // 8 MB
    unsigned short* w_b    = (unsigned short*)(ws + 16777216);            // 32 KB
    unsigned short* cw     = (unsigned short*)(ws + 16809984);            // 8 MB

    hipLaunchKernelGGL(bd_convert_kernel, dim3(2048), dim3(256), 0, stream,
                       data, crit, W, data_b, crit_b, w_b);
    hipLaunchKernelGGL(bd_gemm_cw_kernel, dim3(256), dim3(256), 0, stream,
                       crit_b, w_b, cw);
    hipLaunchKernelGGL(bd_gemm_main_kernel, dim3(16, 16, 16), dim3(256), 0, stream,
                       data_b, cw, out);
}